// Round 2
// baseline (182.418 us; speedup 1.0000x reference)
//
#include <hip/hip_runtime.h>
#include <hip/hip_bf16.h>

// Problem: MultiHeadGraphAttentionLayer_28956669509709  (fp32 I/O per reference)
// Identity: sum_j softmax(e)[...,j] == 1  =>  attention is a no-op, out = hp.
// out[b,n,h*64+d] = a*hp[h,b,n,d] + (1-a)*h[b,n,h*64+d],  a = clip(res_alpha,0,1)
// Fold residual into the weight:  out = h @ (a*Wc + (1-a)*I256)   (Wc block-diag)
// => ONE pure GEMM [16384x256] @ [256x256] (bf16 MFMA, fp32 acc), no epilogue blend.
// adj (134 MB fp32) is never touched.
//
// R2 changes vs R1:
//  - residual folded into packed weight (pack_w adds (1-a)*I, scales by a):
//    epilogue is pure acc->store; no LDS re-read, no alpha on the hot path
//  - B-fragment loads software-pipelined: kt=0 prefetched before the barrier,
//    kt+1 loads issued over kt's MFMAs

typedef unsigned short ushort_t;
typedef __bf16 bf16x8 __attribute__((ext_vector_type(8)));
typedef float floatx4 __attribute__((ext_vector_type(4)));

__device__ __forceinline__ ushort_t f2bf(float f) {
    unsigned int x;
    __builtin_memcpy(&x, &f, 4);
    // round to nearest even
    return (ushort_t)((x + 0x7fffu + ((x >> 16) & 1u)) >> 16);
}

// ---------------------------------------------------------------------------
// Kernel 1: W fp32 [H=4][F=256][D=64] -> Wb bf16 in MFMA fragment order,
// with the residual folded in:
//   val(k,n) = a*Wc[k][n] + (1-a)*(k==n),  k=f global, n=h*64+d
//   Wb[h][kt][nt][lane][j] = bf16( val( kt*32+(lane>>4)*8+j, h*64+nt*16+(lane&15) ) )
// Each B-fragment load in the GEMM is then a single coalesced 1KiB wave read.
// grid: 16 blocks (h = bid>>2, f-chunk = bid&3), 256 threads
// ---------------------------------------------------------------------------
__global__ __launch_bounds__(256) void pack_w(const float* __restrict__ W,
                                              const float* __restrict__ alpha_p,
                                              ushort_t* __restrict__ Wb) {
    __shared__ float tile[64][68];  // [f_local][d], +4 pad breaks bank stride
    const int h  = blockIdx.x >> 2;
    const int f0 = (blockIdx.x & 3) * 64;
    const int t  = threadIdx.x;

    float av = *alpha_p;
    av = fminf(fmaxf(av, 0.0f), 1.0f);
    const float bv = 1.0f - av;

    // coalesced fp32 load (d contiguous per f-row) into LDS (keep fp32)
    #pragma unroll
    for (int p = 0; p < 2; ++p) {
        const int fl = p * 32 + (t >> 3);
        const int d0 = (t & 7) * 8;
        const float* src = W + h * 16384 + (f0 + fl) * 64 + d0;
        *(float4*)&tile[fl][d0]     = *(const float4*)(src);
        *(float4*)&tile[fl][d0 + 4] = *(const float4*)(src + 4);
    }
    __syncthreads();

    // write packed fragments: this f-chunk covers kt = f0/32 .. f0/32+1
    #pragma unroll
    for (int p = 0; p < 2; ++p) {
        const int c    = p * 256 + t;    // 512 fragment-chunks of 8 elements
        const int kt2  = c >> 8;         // 0..1 (local kt within this f-chunk)
        const int nt   = (c >> 6) & 3;
        const int lane = c & 63;
        const int kt   = (f0 >> 5) + kt2;
        const int d    = nt * 16 + (lane & 15);   // 0..63, col n = h*64+d
        const int nglb = h * 64 + d;
        ushort_t tmp[8];
        #pragma unroll
        for (int j = 0; j < 8; ++j) {
            const int kglb = f0 + kt2 * 32 + ((lane >> 4) * 8) + j;
            float v = av * tile[kt2 * 32 + (lane >> 4) * 8 + j][d];
            if (kglb == nglb) v += bv;   // folded (1-a)*I
            tmp[j] = f2bf(v);
        }
        *(uint4*)(Wb + (size_t)(((h * 8 + kt) * 4 + nt) * 64 + lane) * 8) =
            *(const uint4*)tmp;
    }
}

// ---------------------------------------------------------------------------
// Kernel 2: out = h @ W'   (fp32 in/out, bf16 MFMA inside, residual pre-folded)
//   grid: 512 blocks x 256 threads; block tile = 32 rows x 256 cols
//   wave w = head w: 32 rows x cols [w*64, w*64+64) -> acc[2][4] of 16x16x32
// ---------------------------------------------------------------------------
#define LDS_STRIDE 264  // 256 + 8 pad

__global__ __launch_bounds__(256) void gat_gemm(const float* __restrict__ hIn,
                                                const ushort_t* __restrict__ Wb,
                                                float* __restrict__ out) {
    __shared__ ushort_t hA[32 * LDS_STRIDE];
    const int t  = threadIdx.x;
    const int m0 = blockIdx.x * 32;

    const int w    = t >> 6;   // head index, cols [w*64, w*64+64)
    const int lane = t & 63;
    const int quad = lane >> 4;
    const int l16  = lane & 15;

    // B-fragment base for this head+lane; + kt*2048 + nt*512 walks fragments
    const ushort_t* wbase = Wb + (size_t)w * 16384 + lane * 8;

    // prefetch kt=0 B fragments BEFORE staging/barrier (hides W load latency)
    bf16x8 b[4];
    #pragma unroll
    for (int nt = 0; nt < 4; ++nt)
        b[nt] = *(const bf16x8*)(wbase + nt * 512);

    // stage 32x256 fp32 h-tile -> bf16 LDS, coalesced float4 loads
    #pragma unroll
    for (int i = 0; i < 4; ++i) {
        const int c   = i * 256 + t;      // 1024 chunks of 8 elements
        const int row = c >> 5;
        const int k8  = (c & 31) * 8;
        const float* src = hIn + (size_t)(m0 + row) * 256 + k8;
        float4 v0 = *(const float4*)(src);
        float4 v1 = *(const float4*)(src + 4);
        ushort_t tmp[8] = { f2bf(v0.x), f2bf(v0.y), f2bf(v0.z), f2bf(v0.w),
                            f2bf(v1.x), f2bf(v1.y), f2bf(v1.z), f2bf(v1.w) };
        *(uint4*)(hA + row * LDS_STRIDE + k8) = *(const uint4*)tmp;
    }
    __syncthreads();

    floatx4 acc[2][4] = {};

    #pragma unroll
    for (int kt = 0; kt < 8; ++kt) {
        // software-pipeline: issue kt+1 B loads over kt's LDS reads + MFMAs
        bf16x8 bn[4];
        if (kt < 7) {
            #pragma unroll
            for (int nt = 0; nt < 4; ++nt)
                bn[nt] = *(const bf16x8*)(wbase + (kt + 1) * 2048 + nt * 512);
        }
        const int k0 = kt * 32 + quad * 8;
        bf16x8 a[2];
        #pragma unroll
        for (int mt = 0; mt < 2; ++mt)
            a[mt] = *(const bf16x8*)(hA + (mt * 16 + l16) * LDS_STRIDE + k0);
        #pragma unroll
        for (int mt = 0; mt < 2; ++mt)
            #pragma unroll
            for (int nt = 0; nt < 4; ++nt)
                acc[mt][nt] = __builtin_amdgcn_mfma_f32_16x16x32_bf16(
                    a[mt], b[nt], acc[mt][nt], 0, 0, 0);
        if (kt < 7) {
            #pragma unroll
            for (int nt = 0; nt < 4; ++nt) b[nt] = bn[nt];
        }
    }

    // epilogue: pure store (residual already folded into W')
    // C/D layout (m89-verified): col = lane&15, row = quad*4 + reg
    #pragma unroll
    for (int mt = 0; mt < 2; ++mt) {
        #pragma unroll
        for (int r = 0; r < 4; ++r) {
            const int rl = mt * 16 + quad * 4 + r;
            #pragma unroll
            for (int nt = 0; nt < 4; ++nt) {
                const int col = w * 64 + nt * 16 + l16;
                out[(size_t)(m0 + rl) * 256 + col] = acc[mt][nt][r];
            }
        }
    }
}

extern "C" void kernel_launch(void* const* d_in, const int* in_sizes, int n_in,
                              void* d_out, int out_size, void* d_ws, size_t ws_size,
                              hipStream_t stream) {
    // inputs (setup_inputs order, all fp32 per reference):
    //   d_in[0] h [8,2048,256], d_in[1] adj [8,2048,2048] (UNUSED),
    //   d_in[2] W [4,256,64],   d_in[3] res_alpha scalar
    const float* h_ptr = (const float*)d_in[0];
    const float* W_ptr = (const float*)d_in[2];
    const float* a_ptr = (const float*)d_in[3];
    float* out_ptr     = (float*)d_out;
    ushort_t* Wb       = (ushort_t*)d_ws;  // 4*8*4*64*8*2 = 128 KB scratch

    pack_w<<<16, 256, 0, stream>>>(W_ptr, a_ptr, Wb);
    gat_gemm<<<512, 256, 0, stream>>>(h_ptr, Wb, out_ptr);
}